// Round 8
// baseline (132.783 us; speedup 1.0000x reference)
//
#include <hip/hip_runtime.h>
#include <hip/hip_bf16.h>

// PRNN R8: GRU(NH=128, T=32) + MLP head, B=16384.
// BT=16, BLK=512 (8 waves), grid=1024. LDS-pipe fix: xi/bias C-init LDS reads
// replaced by a 5th K-slice MFMA — patch B-frag pB (k0=p0,k1=p1,k2=1) against
// register A-frags [w_ih | bias]. n-gate xi kept in separate acc aXn (not scaled
// by r). Per-wave-step LDS reads: 10 -> 5 b128. w1/w2 A-frags via d_ws through L1.

#define NSTEP 32
#define BT    16
#define BLK   512

using s8v = __attribute__((ext_vector_type(8))) short;   // 8 bf16
using f4v = __attribute__((ext_vector_type(4))) float;   // MFMA acc

#define L2E 1.4426950408889634f
#define LN2 0.6931471805599453f

__device__ __forceinline__ unsigned short f2bf(float f) {
  __hip_bfloat16 h = __float2bfloat16(f);
  return __builtin_bit_cast(unsigned short, h);
}
__device__ __forceinline__ unsigned pkbf2(float a, float b) {
  return (unsigned)f2bf(a) | ((unsigned)f2bf(b) << 16);
}
__device__ __forceinline__ s8v pack8s(float sc, float4 u, float4 v) {
  s8v a;
  a[0]=(short)f2bf(sc*u.x); a[1]=(short)f2bf(sc*u.y); a[2]=(short)f2bf(sc*u.z); a[3]=(short)f2bf(sc*u.w);
  a[4]=(short)f2bf(sc*v.x); a[5]=(short)f2bf(sc*v.y); a[6]=(short)f2bf(sc*v.z); a[7]=(short)f2bf(sc*v.w);
  return a;
}
__device__ __forceinline__ f4v mfma16(s8v a, s8v b, f4v c) {
  return __builtin_amdgcn_mfma_f32_16x16x32_bf16(a, b, c, 0, 0, 0);
}
__device__ __forceinline__ float sigm2(float x) {    // arg pre-scaled by L2E
  return __builtin_amdgcn_rcpf(1.f + __builtin_amdgcn_exp2f(-x));
}
__device__ __forceinline__ float tanh2(float x) {    // arg pre-scaled by 2*L2E
  return __builtin_fmaf(2.f, __builtin_amdgcn_rcpf(1.f + __builtin_amdgcn_exp2f(-x)), -1.f);
}

// ---- prep: pack w1 (32 KB) and w2 (4 KB) A-frags into d_ws ----
__global__ void prep_kernel(const float* __restrict__ w1, const float* __restrict__ w2,
                            unsigned char* __restrict__ ws) {
  const int task = blockIdx.x;       // 0..35
  const int l = threadIdx.x;         // 0..63
  if (task < 32) {                   // w1 frags: [mt(8)][ks(4)][lane]
    const int mt = task >> 2, ks = task & 3;
    const float* src = w1 + (16*mt + (l & 15)) * 128 + ks*32 + (l >> 4)*8;
    *(s8v*)(ws + (task*64 + l)*16) = pack8s(1.f, *(const float4*)src, *(const float4*)(src + 4));
  } else {                           // w2 frags: [ks(4)][lane], rows<4 real
    const int ks = task - 32;
    s8v fr;
    #pragma unroll
    for (int e = 0; e < 8; ++e) fr[e] = (short)0;
    if ((l & 15) < 4) {
      const float* src = w2 + (l & 15) * 128 + ks*32 + (l >> 4)*8;
      fr = pack8s(1.f, *(const float4*)src, *(const float4*)(src + 4));
    }
    *(s8v*)(ws + 32768 + (ks*64 + l)*16) = fr;
  }
}

__global__ __launch_bounds__(BLK, 4) void prnn_kernel(
    const float* __restrict__ x, const float* __restrict__ w_ih,
    const float* __restrict__ w_hh, const float* __restrict__ b_ih,
    const float* __restrict__ b_hh, const float* __restrict__ b1,
    const float* __restrict__ b2, const unsigned char* __restrict__ ws,
    float* __restrict__ out) {

  __shared__ __align__(16) unsigned char lds_h[4*64*16];     // 4 KB  h B-frags
  __shared__ __align__(16) unsigned char lds_hid[4*64*16];   // 4 KB  hid B-frags
  __shared__ __align__(16) float lds_b2[4];
  __shared__ unsigned lds_idx[16*8];                         // 0.5 KB
  __shared__ float lds_lp[8][16];                            // 0.5 KB

  const int tid = threadIdx.x;
  const int bbase = blockIdx.x * BT;
  const int lane = tid & 63;
  const int lg = lane >> 4, ln = lane & 15;
  const int w = __builtin_amdgcn_readfirstlane(tid >> 6);   // wave 0..7

  // ---- init: patch indices (16 seqs x 8 u32) ----
  if (tid < 128) {
    int b = tid >> 3, ch = tid & 7;
    const float* xp = x + (size_t)(bbase + b) * 64 + ch * 8;
    float4 v0 = *(const float4*)xp, v1 = *(const float4*)(xp + 4);
    unsigned pk = ((v0.x!=0.f?1u:0u) | (v0.y!=0.f?2u:0u))
               | (((v0.z!=0.f?1u:0u) | (v0.w!=0.f?2u:0u)) << 8)
               | (((v1.x!=0.f?1u:0u) | (v1.y!=0.f?2u:0u)) << 16)
               | (((v1.z!=0.f?1u:0u) | (v1.w!=0.f?2u:0u)) << 24);
    lds_idx[b*8 + ch] = pk;
  }
  if (tid < 4) lds_b2[tid] = b2[tid];

  // ---- register weights: w_hh r/z/n A-frags for this wave's 16-row slice ----
  s8v Ar[4], Az[4], An[4];
  {
    const int row = 16*w + ln;
    #pragma unroll
    for (int ks = 0; ks < 4; ++ks) {
      const float* s0 = w_hh + row*128 + ks*32 + lg*8;
      Ar[ks] = pack8s(L2E, *(const float4*)s0, *(const float4*)(s0 + 4));
      const float* s1 = s0 + 128*128;
      Az[ks] = pack8s(L2E, *(const float4*)s1, *(const float4*)(s1 + 4));
      const float* s2 = s0 + 256*128;
      An[ks] = pack8s(2.f*L2E, *(const float4*)s2, *(const float4*)(s2 + 4));
    }
  }
  // ---- xi A-frags: k=0 -> w_ih[:,0], k=1 -> w_ih[:,1], k=2 -> bias ----
  // r,z: bias = b_ih+b_hh, scale L2E.  n: bias = b_ih only, scale 2*L2E.
  s8v ArX, AzX, AnX;
  {
    #pragma unroll
    for (int e = 0; e < 8; ++e) { ArX[e]=(short)0; AzX[e]=(short)0; AnX[e]=(short)0; }
    const int row = 16*w + ln;
    if (lg == 0) {
      ArX[0] = (short)f2bf(L2E * w_ih[2*row]);
      ArX[1] = (short)f2bf(L2E * w_ih[2*row+1]);
      ArX[2] = (short)f2bf(L2E * (b_ih[row] + b_hh[row]));
      const int rz = 128 + row;
      AzX[0] = (short)f2bf(L2E * w_ih[2*rz]);
      AzX[1] = (short)f2bf(L2E * w_ih[2*rz+1]);
      AzX[2] = (short)f2bf(L2E * (b_ih[rz] + b_hh[rz]));
      const int rn = 256 + row;
      AnX[0] = (short)f2bf(2.f*L2E * w_ih[2*rn]);
      AnX[1] = (short)f2bf(2.f*L2E * w_ih[2*rn+1]);
      AnX[2] = (short)f2bf(2.f*L2E * b_ih[rn]);
    }
  }
  // ---- register biases (C-inits) ----
  const int q = 4*w + lg;
  f4v bhnr, b1i;
  {
    const f4v bh = *(const f4v*)(b_hh + 256 + q*4);
    bhnr[0]=(2.f*L2E)*bh[0]; bhnr[1]=(2.f*L2E)*bh[1]; bhnr[2]=(2.f*L2E)*bh[2]; bhnr[3]=(2.f*L2E)*bh[3];
    b1i = *(const f4v*)(b1 + q*4);
  }
  const s8v* __restrict__ wsf = (const s8v*)ws;   // [0..2048) w1 frags, [2048..2304) w2

  __syncthreads();

  // ---- per-lane packed patch history for batch col ln (2 bits/step) ----
  unsigned pk0a = 0, pk0b = 0;
  #pragma unroll
  for (int w8 = 0; w8 < 4; ++w8) {
    unsigned u = lds_idx[ln*8 + w8];
    pk0a |= (((u&3u) | ((u>>6)&0xCu) | ((u>>12)&0x30u) | ((u>>18)&0xC0u)) << (8*w8));
    unsigned u2 = lds_idx[ln*8 + 4 + w8];
    pk0b |= (((u2&3u) | ((u2>>6)&0xCu) | ((u2>>12)&0x30u) | ((u2>>18)&0xC0u)) << (8*w8));
  }

  // C-frag -> B-frag write offset (h and hid share the pattern)
  const unsigned wroff =
      (unsigned)((((w>>1)*64 + 16*(2*(w&1) + (lg>>1)) + ln)*16) + 8*(lg&1));

  s8v Bf[4];
  #pragma unroll
  for (int ks = 0; ks < 4; ++ks)
    #pragma unroll
    for (int e = 0; e < 8; ++e) Bf[ks][e] = (short)0;
  f4v hfr;
  hfr[0]=0.f; hfr[1]=0.f; hfr[2]=0.f; hfr[3]=0.f;
  float lp0 = 0.f;
  int pv0 = 0;

  for (int tb = 0; tb < NSTEP; tb += 8) {
    const unsigned pc0 = (tb & 16) ? pk0b : pk0a;
    #pragma unroll
    for (int k = 0; k < 8; ++k) {
      const int t = tb + k;
      // ---- P1: gate MFMAs (xi via pB MFMA) + gate math + h write ----
      {
        // patch B-frag: k=0 -> p0, k=1 -> p1, k=2 -> 1.0 (lg==0 lanes only)
        uint4 pbu;
        unsigned e01 = ((pv0 & 1) ? 0x3F80u : 0u) | ((pv0 & 2) ? 0x3F800000u : 0u);
        pbu.x = (lg == 0) ? e01 : 0u;
        pbu.y = (lg == 0) ? 0x3F80u : 0u;
        pbu.z = 0u; pbu.w = 0u;
        const s8v pB = __builtin_bit_cast(s8v, pbu);
        const f4v z4 = {0.f, 0.f, 0.f, 0.f};
        f4v aR  = mfma16(ArX, pB, z4);
        f4v aZ  = mfma16(AzX, pB, z4);
        f4v aXn = mfma16(AnX, pB, z4);
        f4v aN  = bhnr;
        #pragma unroll
        for (int ks = 0; ks < 4; ++ks) {
          aR = mfma16(Ar[ks], Bf[ks], aR);
          aZ = mfma16(Az[ks], Bf[ks], aZ);
          aN = mfma16(An[ks], Bf[ks], aN);
        }
        f4v hn;
        #pragma unroll
        for (int r = 0; r < 4; ++r) {
          float R  = sigm2(aR[r]);
          float Z  = sigm2(aZ[r]);
          float Ng = tanh2(__builtin_fmaf(R, aN[r], aXn[r]));
          hn[r] = __builtin_fmaf(Z, hfr[r] - Ng, Ng);
        }
        hfr = hn;
        uint2 wv;
        wv.x = pkbf2(hn[0], hn[1]);
        wv.y = pkbf2(hn[2], hn[3]);
        *(uint2*)(&lds_h[wroff]) = wv;
      }
      __syncthreads();                           // B1: h(t) complete
      // ---- Bf reload (feeds P4 now and P1 of t+1) ----
      #pragma unroll
      for (int ks = 0; ks < 4; ++ks)
        Bf[ks] = *(const s8v*)(&lds_h[(ks*64 + lane)*16]);
      // ---- P4: hid = relu(W1 h + b1); w1 frags from ws via L1 ----
      {
        f4v hc = b1i;
        #pragma unroll
        for (int ks = 0; ks < 4; ++ks)
          hc = mfma16(wsf[(w*4 + ks)*64 + lane], Bf[ks], hc);
        uint2 wv;
        wv.x = pkbf2(fmaxf(hc[0],0.f), fmaxf(hc[1],0.f));
        wv.y = pkbf2(fmaxf(hc[2],0.f), fmaxf(hc[3],0.f));
        *(uint2*)(&lds_hid[wroff]) = wv;
      }
      __syncthreads();                           // B2: hid(t) complete
      // ---- current patch ----
      const int ic0 = (int)((pc0 >> ((2*t) & 31)) & 3);
      // ---- P5: logits + log-softmax gather (rotating wave) ----
      if (w == k) {
        f4v la;
        if (lg == 0) la = *(const f4v*)lds_b2;
        else { la[0]=0.f; la[1]=0.f; la[2]=0.f; la[3]=0.f; }
        #pragma unroll
        for (int ks = 0; ks < 4; ++ks)
          la = mfma16(wsf[2048 + ks*64 + lane],
                      *(const s8v*)(&lds_hid[(ks*64 + lane)*16]), la);
        if (lg == 0) {
          float l0=la[0], l1=la[1], l2=la[2], l3=la[3];
          float m = fmaxf(fmaxf(l0, l1), fmaxf(l2, l3));
          float s = __builtin_amdgcn_exp2f((l0-m)*L2E) + __builtin_amdgcn_exp2f((l1-m)*L2E)
                  + __builtin_amdgcn_exp2f((l2-m)*L2E) + __builtin_amdgcn_exp2f((l3-m)*L2E);
          float sel = (ic0 == 0) ? l0 : (ic0 == 1) ? l1 : (ic0 == 2) ? l2 : l3;
          lp0 += (sel - m) - __builtin_amdgcn_logf(s) * LN2;
        }
      }
      pv0 = ic0;    // teacher-forcing input for step t+1
    }
  }

  // ---- cross-wave logp reduction ----
  if (lg == 0) lds_lp[w][ln] = lp0;
  __syncthreads();
  if (tid < 16) {
    float s = 0.f;
    #pragma unroll
    for (int ww = 0; ww < 8; ++ww) s += lds_lp[ww][tid];
    out[bbase + tid] = s;
  }
}

extern "C" void kernel_launch(void* const* d_in, const int* in_sizes, int n_in,
                              void* d_out, int out_size, void* d_ws, size_t ws_size,
                              hipStream_t stream) {
  const float* x    = (const float*)d_in[0];
  const float* w_ih = (const float*)d_in[1];
  const float* w_hh = (const float*)d_in[2];
  const float* b_ih = (const float*)d_in[3];
  const float* b_hh = (const float*)d_in[4];
  const float* w1   = (const float*)d_in[5];
  const float* b1   = (const float*)d_in[6];
  const float* w2   = (const float*)d_in[7];
  const float* b2   = (const float*)d_in[8];
  float* out = (float*)d_out;
  unsigned char* ws = (unsigned char*)d_ws;      // needs 36 KB

  prep_kernel<<<36, 64, 0, stream>>>(w1, w2, ws);

  int B = in_sizes[0] / 64;          // 16384
  int grid = B / BT;                 // 1024
  prnn_kernel<<<grid, BLK, 0, stream>>>(x, w_ih, w_hh, b_ih, b_hh, b1, b2, ws, out);
}

// Round 9
// 110.015 us; speedup vs baseline: 1.2070x; 1.2070x over previous
//
#include <hip/hip_runtime.h>
#include <hip/hip_bf16.h>

// PRNN R9: GRU(NH=128, T=32) + MLP head, B=16384.
// = R7 (BT=16, 8 waves, grid=1024, xi/bias LDS tables, w1/w2 frags via d_ws/L1)
// restructured to ONE barrier per step: dbuf lds_h/lds_hid on t&1;
// Phase A = P1(gates)+h-write | barrier | Phase B = Bf reload + P4 + P5(t-1).
// #pragma unroll 1 on the t-loop to keep register pressure at R7's no-spill level.

#define NSTEP 32
#define BT    16
#define BLK   512

using s8v = __attribute__((ext_vector_type(8))) short;   // 8 bf16
using f4v = __attribute__((ext_vector_type(4))) float;   // MFMA acc

#define L2E 1.4426950408889634f
#define LN2 0.6931471805599453f

__device__ __forceinline__ unsigned short f2bf(float f) {
  __hip_bfloat16 h = __float2bfloat16(f);
  return __builtin_bit_cast(unsigned short, h);
}
__device__ __forceinline__ unsigned pkbf2(float a, float b) {
  return (unsigned)f2bf(a) | ((unsigned)f2bf(b) << 16);
}
__device__ __forceinline__ s8v pack8s(float sc, float4 u, float4 v) {
  s8v a;
  a[0]=(short)f2bf(sc*u.x); a[1]=(short)f2bf(sc*u.y); a[2]=(short)f2bf(sc*u.z); a[3]=(short)f2bf(sc*u.w);
  a[4]=(short)f2bf(sc*v.x); a[5]=(short)f2bf(sc*v.y); a[6]=(short)f2bf(sc*v.z); a[7]=(short)f2bf(sc*v.w);
  return a;
}
__device__ __forceinline__ f4v mfma16(s8v a, s8v b, f4v c) {
  return __builtin_amdgcn_mfma_f32_16x16x32_bf16(a, b, c, 0, 0, 0);
}
__device__ __forceinline__ float sigm2(float x) {    // arg pre-scaled by L2E
  return __builtin_amdgcn_rcpf(1.f + __builtin_amdgcn_exp2f(-x));
}
__device__ __forceinline__ float tanh2(float x) {    // arg pre-scaled by 2*L2E
  return __builtin_fmaf(2.f, __builtin_amdgcn_rcpf(1.f + __builtin_amdgcn_exp2f(-x)), -1.f);
}

// ---- prep: pack w1 (32 KB) and w2 (4 KB) A-frags into d_ws ----
__global__ void prep_kernel(const float* __restrict__ w1, const float* __restrict__ w2,
                            unsigned char* __restrict__ ws) {
  const int task = blockIdx.x;       // 0..35
  const int l = threadIdx.x;         // 0..63
  if (task < 32) {                   // w1 frags: [mt(8)][ks(4)][lane]
    const int mt = task >> 2, ks = task & 3;
    const float* src = w1 + (16*mt + (l & 15)) * 128 + ks*32 + (l >> 4)*8;
    *(s8v*)(ws + (task*64 + l)*16) = pack8s(1.f, *(const float4*)src, *(const float4*)(src + 4));
  } else {                           // w2 frags: [ks(4)][lane], rows<4 real
    const int ks = task - 32;
    s8v fr;
    #pragma unroll
    for (int e = 0; e < 8; ++e) fr[e] = (short)0;
    if ((l & 15) < 4) {
      const float* src = w2 + (l & 15) * 128 + ks*32 + (l >> 4)*8;
      fr = pack8s(1.f, *(const float4*)src, *(const float4*)(src + 4));
    }
    *(s8v*)(ws + 32768 + (ks*64 + l)*16) = fr;
  }
}

__global__ __launch_bounds__(BLK, 4) void prnn_kernel(
    const float* __restrict__ x, const float* __restrict__ w_ih,
    const float* __restrict__ w_hh, const float* __restrict__ b_ih,
    const float* __restrict__ b_hh, const float* __restrict__ b1,
    const float* __restrict__ b2, const unsigned char* __restrict__ ws,
    float* __restrict__ out) {

  __shared__ __align__(16) unsigned char lds_h[2][4*64*16];   // 8 KB  h B-frags (dbuf)
  __shared__ __align__(16) unsigned char lds_hid[2][4*64*16]; // 8 KB  hid B-frags (dbuf)
  __shared__ __align__(16) float lds_xrz[64*4*4];             // 4 KB  xi r,z (*L2E)
  __shared__ __align__(16) float lds_xn[32*4*4];              // 2 KB  xi n (*2L2E)
  __shared__ __align__(16) float lds_bb[256];                 // 1 KB  bhn*2L2E | b1
  __shared__ __align__(16) float lds_b2[4];
  __shared__ unsigned lds_idx[16*8];                          // 0.5 KB
  __shared__ float lds_lp[8][16];                             // 0.5 KB

  const int tid = threadIdx.x;
  const int bbase = blockIdx.x * BT;
  const int lane = tid & 63;
  const int lg = lane >> 4, ln = lane & 15;
  const int w = __builtin_amdgcn_readfirstlane(tid >> 6);   // wave 0..7

  // ---- init: patch indices (16 seqs x 8 u32) ----
  if (tid < 128) {
    int b = tid >> 3, ch = tid & 7;
    const float* xp = x + (size_t)(bbase + b) * 64 + ch * 8;
    float4 v0 = *(const float4*)xp, v1 = *(const float4*)(xp + 4);
    unsigned pk = ((v0.x!=0.f?1u:0u) | (v0.y!=0.f?2u:0u))
               | (((v0.z!=0.f?1u:0u) | (v0.w!=0.f?2u:0u)) << 8)
               | (((v1.x!=0.f?1u:0u) | (v1.y!=0.f?2u:0u)) << 16)
               | (((v1.z!=0.f?1u:0u) | (v1.w!=0.f?2u:0u)) << 24);
    lds_idx[b*8 + ch] = pk;
  }
  // ---- init: xi tables (prescaled to exp2 domain) ----
  if (tid < 256) {                              // rows 0..255 (r,z) * L2E
    int j = tid;
    float base = b_ih[j] + b_hh[j];
    float wa = w_ih[2*j], wb = w_ih[2*j+1];
    int qq = j >> 2, e = j & 3;
    #pragma unroll
    for (int v = 0; v < 4; ++v)
      lds_xrz[(qq*4+v)*4 + e] = L2E * (base + ((v&1) ? wa : 0.f) + ((v&2) ? wb : 0.f));
  }
  if (tid < 128) {                              // rows 256..383 (n) * 2L2E
    int j2 = 256 + tid;
    float bn = b_ih[j2];
    float wan = w_ih[2*j2], wbn = w_ih[2*j2+1];
    int qn = tid >> 2, en = tid & 3;
    #pragma unroll
    for (int v = 0; v < 4; ++v)
      lds_xn[(qn*4+v)*4 + en] = (2.f*L2E) * (bn + ((v&1) ? wan : 0.f) + ((v&2) ? wbn : 0.f));
  }
  if (tid < 128) lds_bb[tid] = (2.f*L2E) * b_hh[256 + tid];
  else if (tid < 256) lds_bb[tid] = b1[tid - 128];
  if (tid < 4) lds_b2[tid] = b2[tid];

  // ---- register weights: w_hh r/z/n A-frags for this wave's 16-row slice ----
  s8v Ar[4], Az[4], An[4];
  {
    const int row = 16*w + ln;
    #pragma unroll
    for (int ks = 0; ks < 4; ++ks) {
      const float* s0 = w_hh + row*128 + ks*32 + lg*8;
      Ar[ks] = pack8s(L2E, *(const float4*)s0, *(const float4*)(s0 + 4));
      const float* s1 = s0 + 128*128;
      Az[ks] = pack8s(L2E, *(const float4*)s1, *(const float4*)(s1 + 4));
      const float* s2 = s0 + 256*128;
      An[ks] = pack8s(2.f*L2E, *(const float4*)s2, *(const float4*)(s2 + 4));
    }
  }
  const int q = 4*w + lg;
  const s8v* __restrict__ wsf = (const s8v*)ws;   // [0..2048) w1 frags, [2048..2304) w2

  __syncthreads();

  // ---- per-lane packed patch history for batch col ln (2 bits/step) ----
  unsigned pk0a = 0, pk0b = 0;
  #pragma unroll
  for (int w8 = 0; w8 < 4; ++w8) {
    unsigned u = lds_idx[ln*8 + w8];
    pk0a |= (((u&3u) | ((u>>6)&0xCu) | ((u>>12)&0x30u) | ((u>>18)&0xC0u)) << (8*w8));
    unsigned u2 = lds_idx[ln*8 + 4 + w8];
    pk0b |= (((u2&3u) | ((u2>>6)&0xCu) | ((u2>>12)&0x30u) | ((u2>>18)&0xC0u)) << (8*w8));
  }

  // C-frag -> B-frag write offset (h and hid share the pattern)
  const unsigned wroff =
      (unsigned)((((w>>1)*64 + 16*(2*(w&1) + (lg>>1)) + ln)*16) + 8*(lg&1));

  s8v Bf[4];
  #pragma unroll
  for (int ks = 0; ks < 4; ++ks)
    #pragma unroll
    for (int e = 0; e < 8; ++e) Bf[ks][e] = (short)0;
  f4v hfr;
  hfr[0]=0.f; hfr[1]=0.f; hfr[2]=0.f; hfr[3]=0.f;
  float lp0 = 0.f;
  int pv0 = 0;

  // P5 body: logits + log-softmax gather for step u (rotating wave w == u&7)
  auto do_p5 = [&](int u, int uslot) {
    if (w == (u & 7)) {
      f4v la;
      if (lg == 0) la = *(const f4v*)lds_b2;
      else { la[0]=0.f; la[1]=0.f; la[2]=0.f; la[3]=0.f; }
      #pragma unroll
      for (int ks = 0; ks < 4; ++ks)
        la = mfma16(wsf[2048 + ks*64 + lane],
                    *(const s8v*)(&lds_hid[uslot][(ks*64 + lane)*16]), la);
      if (lg == 0) {
        const int ic = (int)((((u & 16) ? pk0b : pk0a) >> ((2*u) & 31)) & 3);
        float l0=la[0], l1=la[1], l2=la[2], l3=la[3];
        float m = fmaxf(fmaxf(l0, l1), fmaxf(l2, l3));
        float s = __builtin_amdgcn_exp2f((l0-m)*L2E) + __builtin_amdgcn_exp2f((l1-m)*L2E)
                + __builtin_amdgcn_exp2f((l2-m)*L2E) + __builtin_amdgcn_exp2f((l3-m)*L2E);
        float sel = (ic == 0) ? l0 : (ic == 1) ? l1 : (ic == 2) ? l2 : l3;
        lp0 += (sel - m) - __builtin_amdgcn_logf(s) * LN2;
      }
    }
  };

  #pragma unroll 1
  for (int t = 0; t < NSTEP; ++t) {
    const int slot = t & 1;
    // ---- Phase A: P1 gate MFMAs (C-init = prescaled xi) + gates + h write ----
    {
      const int var = pv0;
      f4v aR = *(const f4v*)&lds_xrz[(q*4 + var)*4];
      f4v aZ = *(const f4v*)&lds_xrz[((q+32)*4 + var)*4];
      f4v aN = *(const f4v*)&lds_bb[q*4];
      #pragma unroll
      for (int ks = 0; ks < 4; ++ks) {
        aR = mfma16(Ar[ks], Bf[ks], aR);
        aZ = mfma16(Az[ks], Bf[ks], aZ);
        aN = mfma16(An[ks], Bf[ks], aN);
      }
      const f4v xnv = *(const f4v*)&lds_xn[(q*4 + var)*4];
      f4v hn;
      #pragma unroll
      for (int r = 0; r < 4; ++r) {
        float R  = sigm2(aR[r]);
        float Z  = sigm2(aZ[r]);
        float Ng = tanh2(__builtin_fmaf(R, aN[r], xnv[r]));
        hn[r] = __builtin_fmaf(Z, hfr[r] - Ng, Ng);
      }
      hfr = hn;
      uint2 wv;
      wv.x = pkbf2(hn[0], hn[1]);
      wv.y = pkbf2(hn[2], hn[3]);
      *(uint2*)(&lds_h[slot][wroff]) = wv;
    }
    __syncthreads();                           // the ONLY barrier per step
    // ---- Phase B: Bf reload (feeds P1 of t+1 and P4 now) ----
    #pragma unroll
    for (int ks = 0; ks < 4; ++ks)
      Bf[ks] = *(const s8v*)(&lds_h[slot][(ks*64 + lane)*16]);
    // ---- P4: hid = relu(W1 h + b1) -> lds_hid[slot] ----
    {
      f4v hc = *(const f4v*)&lds_bb[128 + q*4];
      #pragma unroll
      for (int ks = 0; ks < 4; ++ks)
        hc = mfma16(wsf[(w*4 + ks)*64 + lane], Bf[ks], hc);
      uint2 wv;
      wv.x = pkbf2(fmaxf(hc[0],0.f), fmaxf(hc[1],0.f));
      wv.y = pkbf2(fmaxf(hc[2],0.f), fmaxf(hc[3],0.f));
      *(uint2*)(&lds_hid[slot][wroff]) = wv;
    }
    // ---- P5 for step t-1 (reads lds_hid[slot^1]; ordered by this step's barrier) ----
    if (t > 0) do_p5(t - 1, slot ^ 1);
    // ---- teacher-forcing input for step t+1 ----
    pv0 = (int)((((t & 16) ? pk0b : pk0a) >> ((2*t) & 31)) & 3);
  }

  // ---- epilogue: P5 for t=31 (hid[1] written in last Phase B) ----
  __syncthreads();
  do_p5(NSTEP - 1, (NSTEP - 1) & 1);

  // ---- cross-wave logp reduction ----
  if (lg == 0) lds_lp[w][ln] = lp0;
  __syncthreads();
  if (tid < 16) {
    float s = 0.f;
    #pragma unroll
    for (int ww = 0; ww < 8; ++ww) s += lds_lp[ww][tid];
    out[bbase + tid] = s;
  }
}

extern "C" void kernel_launch(void* const* d_in, const int* in_sizes, int n_in,
                              void* d_out, int out_size, void* d_ws, size_t ws_size,
                              hipStream_t stream) {
  const float* x    = (const float*)d_in[0];
  const float* w_ih = (const float*)d_in[1];
  const float* w_hh = (const float*)d_in[2];
  const float* b_ih = (const float*)d_in[3];
  const float* b_hh = (const float*)d_in[4];
  const float* w1   = (const float*)d_in[5];
  const float* b1   = (const float*)d_in[6];
  const float* w2   = (const float*)d_in[7];
  const float* b2   = (const float*)d_in[8];
  float* out = (float*)d_out;
  unsigned char* ws = (unsigned char*)d_ws;      // needs 36 KB

  prep_kernel<<<36, 64, 0, stream>>>(w1, w2, ws);

  int B = in_sizes[0] / 64;          // 16384
  int grid = B / BT;                 // 1024
  prnn_kernel<<<grid, BLK, 0, stream>>>(x, w_ih, w_hh, b_ih, b_hh, b1, b2, ws, out);
}